// Round 1
// baseline (168.084 us; speedup 1.0000x reference)
//
#include <hip/hip_runtime.h>
#include <hip/hip_bf16.h>

#define BATCH 4096
#define NTOT  8192
#define DIM   512

typedef __attribute__((ext_vector_type(8))) __bf16 bf16x8;
typedef __attribute__((ext_vector_type(4))) float  floatx4;

__device__ __forceinline__ unsigned short f2bf(float x) {
  union { float f; unsigned u; } v; v.f = x;
  unsigned r = v.u + 0x7fffu + ((v.u >> 16) & 1u);   // RNE
  return (unsigned short)(r >> 16);
}
__device__ __forceinline__ float bf2f(unsigned short u) {
  union { unsigned u; float f; } v; v.u = ((unsigned)u) << 16;
  return v.f;
}

#define ASYNC16(gp, lp)                                                        \
  __builtin_amdgcn_global_load_lds(                                            \
      (__attribute__((address_space(1))) void*)(gp),                           \
      (__attribute__((address_space(3))) void*)(lp), 16, 0, 0)

// ---------------------------------------------------------------- normalize
// One wave per row: read 512 fp32, rsqrt(sum sq), write 512 bf16.
__global__ __launch_bounds__(256) void nrm_kernel(const float* __restrict__ zi,
                                                  const float* __restrict__ zj,
                                                  ushort* __restrict__ zn) {
  const int row = blockIdx.x * 4 + (threadIdx.x >> 6);
  const int l   = threadIdx.x & 63;
  const float* src = (row < BATCH) ? (zi + (size_t)row * DIM)
                                   : (zj + (size_t)(row - BATCH) * DIM);
  const float4* s4 = (const float4*)src;
  float4 v0 = s4[l];
  float4 v1 = s4[l + 64];
  float ss = v0.x*v0.x + v0.y*v0.y + v0.z*v0.z + v0.w*v0.w
           + v1.x*v1.x + v1.y*v1.y + v1.z*v1.z + v1.w*v1.w;
  #pragma unroll
  for (int m = 1; m < 64; m <<= 1) ss += __shfl_xor(ss, m, 64);
  const float r = 1.0f / fmaxf(sqrtf(ss), 1e-12f);
  ushort4 o0, o1;
  o0.x = f2bf(v0.x * r); o0.y = f2bf(v0.y * r);
  o0.z = f2bf(v0.z * r); o0.w = f2bf(v0.w * r);
  o1.x = f2bf(v1.x * r); o1.y = f2bf(v1.y * r);
  o1.z = f2bf(v1.z * r); o1.w = f2bf(v1.w * r);
  ushort4* d4 = (ushort4*)(zn + (size_t)row * DIM);
  d4[l]      = o0;
  d4[l + 64] = o1;
}

// ---------------------------------------------------------------- positives
// p_i = 10 * dot(zn[i], zn[pair(i)]), one wave per row.
__global__ __launch_bounds__(256) void pos_kernel(const ushort* __restrict__ zn,
                                                  float* __restrict__ P) {
  const int row = blockIdx.x * 4 + (threadIdx.x >> 6);
  const int l   = threadIdx.x & 63;
  const int pr  = (row < BATCH) ? row + BATCH : row - BATCH;
  const ushort4* a = (const ushort4*)(zn + (size_t)row * DIM);
  const ushort4* b = (const ushort4*)(zn + (size_t)pr  * DIM);
  float acc = 0.f;
  #pragma unroll
  for (int it = 0; it < 2; ++it) {
    ushort4 ua = a[l + it * 64], ub = b[l + it * 64];
    acc += bf2f(ua.x) * bf2f(ub.x) + bf2f(ua.y) * bf2f(ub.y)
         + bf2f(ua.z) * bf2f(ub.z) + bf2f(ua.w) * bf2f(ub.w);
  }
  #pragma unroll
  for (int m = 1; m < 64; m <<= 1) acc += __shfl_xor(acc, m, 64);
  if (l == 0) P[row] = acc * 10.0f;
}

// ---------------------------------------------------------------- main GEMM
// 128x128 tile per block (4 waves, each 64x64 via 4x4 frags of 16x16x32).
// Epilogue: S[row] += sum_col exp(10*c - 10), diagonal excluded.
__global__ __launch_bounds__(256) void simsum_kernel(const ushort* __restrict__ zn,
                                                     float* __restrict__ S) {
  __shared__ __align__(16) ushort shA[128 * 32];
  __shared__ __align__(16) ushort shB[128 * 32];
  __shared__ float red[256];

  const int t    = threadIdx.x;
  const int w    = t >> 6;
  const int l    = t & 63;
  const int quad = l >> 4;
  const int lo   = l & 15;
  const int wm   = w >> 1;
  const int wn   = w & 1;
  const int tileRow = blockIdx.x * 128;
  const int tileCol = blockIdx.y * 128;

  // staging: chunk c = w*128 + q*64 + l; c -> LDS ushort offset c*8,
  // global Z[tile + (c>>2)][kb + (c&3)*8 .. +8]
  const int c0 = w * 128 + l;
  const int c1 = c0 + 64;
  const ushort* gA0 = zn + (size_t)(tileRow + (c0 >> 2)) * DIM + (c0 & 3) * 8;
  const ushort* gA1 = zn + (size_t)(tileRow + (c1 >> 2)) * DIM + (c1 & 3) * 8;
  const ushort* gB0 = zn + (size_t)(tileCol + (c0 >> 2)) * DIM + (c0 & 3) * 8;
  const ushort* gB1 = zn + (size_t)(tileCol + (c1 >> 2)) * DIM + (c1 & 3) * 8;
  ushort* lA0 = shA + (w * 128) * 8;
  ushort* lA1 = shA + (w * 128 + 64) * 8;
  ushort* lB0 = shB + (w * 128) * 8;
  ushort* lB1 = shB + (w * 128 + 64) * 8;

  floatx4 acc[4][4];
  #pragma unroll
  for (int i = 0; i < 4; ++i)
    #pragma unroll
    for (int j = 0; j < 4; ++j)
      acc[i][j] = (floatx4){0.f, 0.f, 0.f, 0.f};

  const int aOff = (wm * 64 + lo) * 32 + quad * 8;  // + i*512
  const int bOff = (wn * 64 + lo) * 32 + quad * 8;  // + j*512

  for (int kb = 0; kb < DIM; kb += 32) {
    ASYNC16(gA0, lA0); ASYNC16(gA1, lA1);
    ASYNC16(gB0, lB0); ASYNC16(gB1, lB1);
    __syncthreads();  // drains vmcnt -> LDS visible
    bf16x8 aF[4], bF[4];
    #pragma unroll
    for (int i = 0; i < 4; ++i) aF[i] = *(const bf16x8*)(shA + aOff + i * 512);
    #pragma unroll
    for (int j = 0; j < 4; ++j) bF[j] = *(const bf16x8*)(shB + bOff + j * 512);
    #pragma unroll
    for (int i = 0; i < 4; ++i)
      #pragma unroll
      for (int j = 0; j < 4; ++j)
        acc[i][j] = __builtin_amdgcn_mfma_f32_16x16x32_bf16(aF[i], bF[j],
                                                            acc[i][j], 0, 0, 0);
    __syncthreads();  // protect LDS before next stage
    gA0 += 32; gA1 += 32; gB0 += 32; gB1 += 32;
  }

  // epilogue: exp + row-sum. C/D: col = lo, row = quad*4 + r (within 16x16).
  float rs[4][4];
  #pragma unroll
  for (int i = 0; i < 4; ++i)
    #pragma unroll
    for (int r = 0; r < 4; ++r) rs[i][r] = 0.f;

  #pragma unroll
  for (int i = 0; i < 4; ++i) {
    #pragma unroll
    for (int j = 0; j < 4; ++j) {
      const int col = tileCol + wn * 64 + j * 16 + lo;
      #pragma unroll
      for (int r = 0; r < 4; ++r) {
        const int row = tileRow + wm * 64 + i * 16 + quad * 4 + r;
        const float e = __expf(acc[i][j][r] * 10.0f - 10.0f);
        rs[i][r] += (row == col) ? 0.0f : e;
      }
    }
  }
  // reduce across the 16 column-lanes (low 4 lane bits)
  #pragma unroll
  for (int m = 1; m < 16; m <<= 1) {
    #pragma unroll
    for (int i = 0; i < 4; ++i)
      #pragma unroll
      for (int r = 0; r < 4; ++r)
        rs[i][r] += __shfl_xor(rs[i][r], m, 64);
  }
  if (lo == 0) {
    #pragma unroll
    for (int i = 0; i < 4; ++i)
      #pragma unroll
      for (int r = 0; r < 4; ++r)
        red[wn * 128 + wm * 64 + i * 16 + quad * 4 + r] = rs[i][r];
  }
  __syncthreads();
  if (t < 128) atomicAdd(&S[tileRow + t], red[t] + red[128 + t]);
}

// ---------------------------------------------------------------- final loss
__global__ __launch_bounds__(256) void loss_kernel(const float* __restrict__ S,
                                                   const float* __restrict__ P,
                                                   float* __restrict__ out) {
  float acc = 0.f;
  for (int i = threadIdx.x; i < NTOT; i += 256)
    acc += 10.0f + logf(S[i]) - P[i];
  #pragma unroll
  for (int m = 1; m < 64; m <<= 1) acc += __shfl_xor(acc, m, 64);
  __shared__ float sb[4];
  if ((threadIdx.x & 63) == 0) sb[threadIdx.x >> 6] = acc;
  __syncthreads();
  if (threadIdx.x == 0)
    out[0] = (sb[0] + sb[1] + sb[2] + sb[3]) / (float)NTOT;
}

extern "C" void kernel_launch(void* const* d_in, const int* in_sizes, int n_in,
                              void* d_out, int out_size, void* d_ws, size_t ws_size,
                              hipStream_t stream) {
  const float* zi = (const float*)d_in[0];
  const float* zj = (const float*)d_in[1];
  ushort* zn = (ushort*)d_ws;                                  // 8192*512 bf16 = 8 MB
  float*  S  = (float*)((char*)d_ws + (size_t)NTOT * DIM * 2); // 32 KB
  float*  P  = S + NTOT;                                       // 32 KB
  float*  out = (float*)d_out;

  nrm_kernel<<<NTOT / 4, 256, 0, stream>>>(zi, zj, zn);
  pos_kernel<<<NTOT / 4, 256, 0, stream>>>(zn, P);
  hipMemsetAsync(S, 0, NTOT * sizeof(float), stream);
  simsum_kernel<<<dim3(64, 64), 256, 0, stream>>>(zn, S);
  loss_kernel<<<1, 256, 0, stream>>>(S, P, out);
}

// Round 2
// 144.285 us; speedup vs baseline: 1.1649x; 1.1649x over previous
//
#include <hip/hip_runtime.h>
#include <hip/hip_bf16.h>

#define BATCH 4096
#define NTOT  8192
#define DIM   512

typedef __attribute__((ext_vector_type(8))) __bf16 bf16x8;
typedef __attribute__((ext_vector_type(4))) float  floatx4;

__device__ __forceinline__ unsigned short f2bf(float x) {
  union { float f; unsigned u; } v; v.f = x;
  unsigned r = v.u + 0x7fffu + ((v.u >> 16) & 1u);   // RNE
  return (unsigned short)(r >> 16);
}

#define ASYNC16(gp, lp)                                                        \
  __builtin_amdgcn_global_load_lds(                                            \
      (__attribute__((address_space(1))) void*)(gp),                           \
      (__attribute__((address_space(3))) void*)(lp), 16, 0, 0)

// ---------------------------------------------------------------- normalize
// One wave per row: read 512 fp32, rsqrt(sum sq), write 512 bf16.
__global__ __launch_bounds__(256) void nrm_kernel(const float* __restrict__ zi,
                                                  const float* __restrict__ zj,
                                                  ushort* __restrict__ zn) {
  const int row = blockIdx.x * 4 + (threadIdx.x >> 6);
  const int l   = threadIdx.x & 63;
  const float* src = (row < BATCH) ? (zi + (size_t)row * DIM)
                                   : (zj + (size_t)(row - BATCH) * DIM);
  const float4* s4 = (const float4*)src;
  float4 v0 = s4[l];
  float4 v1 = s4[l + 64];
  float ss = v0.x*v0.x + v0.y*v0.y + v0.z*v0.z + v0.w*v0.w
           + v1.x*v1.x + v1.y*v1.y + v1.z*v1.z + v1.w*v1.w;
  #pragma unroll
  for (int m = 1; m < 64; m <<= 1) ss += __shfl_xor(ss, m, 64);
  const float r = 1.0f / fmaxf(sqrtf(ss), 1e-12f);
  ushort4 o0, o1;
  o0.x = f2bf(v0.x * r); o0.y = f2bf(v0.y * r);
  o0.z = f2bf(v0.z * r); o0.w = f2bf(v0.w * r);
  o1.x = f2bf(v1.x * r); o1.y = f2bf(v1.y * r);
  o1.z = f2bf(v1.z * r); o1.w = f2bf(v1.w * r);
  ushort4* d4 = (ushort4*)(zn + (size_t)row * DIM);
  d4[l]      = o0;
  d4[l + 64] = o1;
}

// ---------------------------------------------------------------- main GEMM
// Upper-triangular blocks only (bj >= bi): sim is symmetric, so each
// off-diagonal block contributes row-sums to S[rows] AND col-sums to S[cols].
// Positives extracted on bj == bi+32 blocks (col == row + BATCH).
// LDS XOR swizzle: chunk c holds (row=c>>2, kc=(c&3)^((row>>1)&3)) so that
// fragment reads spread over all 8 bank phases (8-way -> 4-way conflicts).
__global__ __launch_bounds__(256) void simsum_kernel(const ushort* __restrict__ zn,
                                                     float* __restrict__ S,
                                                     float* __restrict__ P) {
  const int bi = blockIdx.x;
  const int bj = blockIdx.y;
  if (bj < bi) return;
  const bool diag = (bi == bj);
  const bool posb = (bj == bi + BATCH / 128);

  __shared__ __align__(16) ushort shA[128 * 32];
  __shared__ __align__(16) ushort shB[128 * 32];
  __shared__ float redR[2][128];
  __shared__ float redC[2][128];

  const int t    = threadIdx.x;
  const int w    = t >> 6;
  const int l    = t & 63;
  const int quad = l >> 4;
  const int lo   = l & 15;
  const int wm   = w >> 1;
  const int wn   = w & 1;
  const int tileRow = bi * 128;
  const int tileCol = bj * 128;

  // staging: lane l of wave w stages chunks c0 = w*128+l and c1 = c0+64 into
  // LDS at chunk*16B. Source k-chunk is XOR-swizzled per the row.
  const int c0 = w * 128 + l;
  const int c1 = c0 + 64;
  const int r0 = c0 >> 2, k0 = ((c0 & 3) ^ ((r0 >> 1) & 3)) * 8;
  const int r1 = c1 >> 2, k1 = ((c1 & 3) ^ ((r1 >> 1) & 3)) * 8;
  const ushort* gA0 = zn + (size_t)(tileRow + r0) * DIM + k0;
  const ushort* gA1 = zn + (size_t)(tileRow + r1) * DIM + k1;
  const ushort* gB0 = zn + (size_t)(tileCol + r0) * DIM + k0;
  const ushort* gB1 = zn + (size_t)(tileCol + r1) * DIM + k1;
  ushort* lA0 = shA + (w * 128) * 8;
  ushort* lA1 = shA + (w * 128 + 64) * 8;
  ushort* lB0 = shB + (w * 128) * 8;
  ushort* lB1 = shB + (w * 128 + 64) * 8;

  floatx4 acc[4][4];
  #pragma unroll
  for (int i = 0; i < 4; ++i)
    #pragma unroll
    for (int j = 0; j < 4; ++j)
      acc[i][j] = (floatx4){0.f, 0.f, 0.f, 0.f};

  // fragment read offsets (ushorts): chunk = R*4 + (quad ^ ((lo>>1)&3))
  const int sw   = (quad ^ ((lo >> 1) & 3)) * 8;
  const int aOff = (wm * 64 + lo) * 32 + sw;  // + i*512
  const int bOff = (wn * 64 + lo) * 32 + sw;  // + j*512

  for (int kb = 0; kb < DIM; kb += 32) {
    ASYNC16(gA0, lA0); ASYNC16(gA1, lA1);
    ASYNC16(gB0, lB0); ASYNC16(gB1, lB1);
    __syncthreads();
    bf16x8 aF[4], bF[4];
    #pragma unroll
    for (int i = 0; i < 4; ++i) aF[i] = *(const bf16x8*)(shA + aOff + i * 512);
    #pragma unroll
    for (int j = 0; j < 4; ++j) bF[j] = *(const bf16x8*)(shB + bOff + j * 512);
    #pragma unroll
    for (int i = 0; i < 4; ++i)
      #pragma unroll
      for (int j = 0; j < 4; ++j)
        acc[i][j] = __builtin_amdgcn_mfma_f32_16x16x32_bf16(aF[i], bF[j],
                                                            acc[i][j], 0, 0, 0);
    __syncthreads();
    gA0 += 32; gA1 += 32; gB0 += 32; gB1 += 32;
  }

  // epilogue. C/D layout: col = lo, row = quad*4 + r (within each 16x16 frag)
  float rs[4][4];
  float cs[4];
  #pragma unroll
  for (int i = 0; i < 4; ++i)
    #pragma unroll
    for (int r = 0; r < 4; ++r) rs[i][r] = 0.f;
  #pragma unroll
  for (int j = 0; j < 4; ++j) cs[j] = 0.f;

  #pragma unroll
  for (int i = 0; i < 4; ++i) {
    #pragma unroll
    for (int j = 0; j < 4; ++j) {
      const int col = tileCol + wn * 64 + j * 16 + lo;
      #pragma unroll
      for (int r = 0; r < 4; ++r) {
        const int row = tileRow + wm * 64 + i * 16 + quad * 4 + r;
        const float v = acc[i][j][r];
        float e = __expf(v * 10.0f - 10.0f);
        if (diag && row == col) e = 0.0f;
        rs[i][r] += e;
        cs[j] += e;
        if (posb && col == row + BATCH) {
          P[row] = v * 10.0f;
          P[row + BATCH] = v * 10.0f;
        }
      }
    }
  }
  // row sums: reduce across the 16 column-lanes (low 4 lane bits)
  #pragma unroll
  for (int m = 1; m < 16; m <<= 1) {
    #pragma unroll
    for (int i = 0; i < 4; ++i)
      #pragma unroll
      for (int r = 0; r < 4; ++r)
        rs[i][r] += __shfl_xor(rs[i][r], m, 64);
  }
  if (lo == 0) {
    #pragma unroll
    for (int i = 0; i < 4; ++i)
      #pragma unroll
      for (int r = 0; r < 4; ++r)
        redR[wn][wm * 64 + i * 16 + quad * 4 + r] = rs[i][r];
  }
  // col sums: reduce across the 4 quads (lane bits 4,5)
  #pragma unroll
  for (int m = 16; m < 64; m <<= 1) {
    #pragma unroll
    for (int j = 0; j < 4; ++j) cs[j] += __shfl_xor(cs[j], m, 64);
  }
  if (quad == 0) {
    #pragma unroll
    for (int j = 0; j < 4; ++j)
      redC[wm][wn * 64 + j * 16 + lo] = cs[j];
  }
  __syncthreads();
  if (t < 128) {
    atomicAdd(&S[tileRow + t], redR[0][t] + redR[1][t]);
  } else if (!diag) {
    const int c = t - 128;
    atomicAdd(&S[tileCol + c], redC[0][c] + redC[1][c]);
  }
}

// ---------------------------------------------------------------- final loss
// 32 blocks x 256 threads; one row per thread; atomicAdd partials into out.
__global__ __launch_bounds__(256) void loss_kernel(const float* __restrict__ S,
                                                   const float* __restrict__ P,
                                                   float* __restrict__ out) {
  const int i = blockIdx.x * 256 + threadIdx.x;
  float v = 10.0f + logf(S[i]) - P[i];
  #pragma unroll
  for (int m = 1; m < 64; m <<= 1) v += __shfl_xor(v, m, 64);
  if ((threadIdx.x & 63) == 0) atomicAdd(out, v * (1.0f / NTOT));
}

extern "C" void kernel_launch(void* const* d_in, const int* in_sizes, int n_in,
                              void* d_out, int out_size, void* d_ws, size_t ws_size,
                              hipStream_t stream) {
  const float* zi = (const float*)d_in[0];
  const float* zj = (const float*)d_in[1];
  ushort* zn = (ushort*)d_ws;                                  // 8192*512 bf16 = 8 MB
  float*  S  = (float*)((char*)d_ws + (size_t)NTOT * DIM * 2); // 32 KB
  float*  P  = S + NTOT;                                       // 32 KB
  float*  out = (float*)d_out;

  nrm_kernel<<<NTOT / 4, 256, 0, stream>>>(zi, zj, zn);
  hipMemsetAsync(S, 0, NTOT * sizeof(float), stream);
  hipMemsetAsync(out, 0, sizeof(float), stream);
  simsum_kernel<<<dim3(64, 64), 256, 0, stream>>>(zn, S, P);
  loss_kernel<<<NTOT / 256, 256, 0, stream>>>(S, P, out);
}

// Round 3
// 123.220 us; speedup vs baseline: 1.3641x; 1.1710x over previous
//
#include <hip/hip_runtime.h>
#include <hip/hip_bf16.h>

#define BATCH 4096
#define NTOT  8192
#define DIM   512

typedef __attribute__((ext_vector_type(8))) __bf16 bf16x8;
typedef __attribute__((ext_vector_type(4))) float  floatx4;

__device__ __forceinline__ unsigned short f2bf(float x) {
  union { float f; unsigned u; } v; v.f = x;
  unsigned r = v.u + 0x7fffu + ((v.u >> 16) & 1u);   // RNE
  return (unsigned short)(r >> 16);
}

#define ASYNC16(gp, lp)                                                        \
  __builtin_amdgcn_global_load_lds(                                            \
      (__attribute__((address_space(1))) void*)(gp),                           \
      (__attribute__((address_space(3))) void*)(lp), 16, 0, 0)

// ---------------------------------------------------------------- normalize
// One wave per row: read 512 fp32, rsqrt(sum sq), write 512 bf16.
// Blocks 0..31 also zero S (8192 floats) so no separate memset dispatch.
__global__ __launch_bounds__(256) void nrm_kernel(const float* __restrict__ zi,
                                                  const float* __restrict__ zj,
                                                  ushort* __restrict__ zn,
                                                  float* __restrict__ S) {
  if (blockIdx.x < 32) S[blockIdx.x * 256 + threadIdx.x] = 0.0f;
  const int row = blockIdx.x * 4 + (threadIdx.x >> 6);
  const int l   = threadIdx.x & 63;
  const float* src = (row < BATCH) ? (zi + (size_t)row * DIM)
                                   : (zj + (size_t)(row - BATCH) * DIM);
  const float4* s4 = (const float4*)src;
  float4 v0 = s4[l];
  float4 v1 = s4[l + 64];
  float ss = v0.x*v0.x + v0.y*v0.y + v0.z*v0.z + v0.w*v0.w
           + v1.x*v1.x + v1.y*v1.y + v1.z*v1.z + v1.w*v1.w;
  #pragma unroll
  for (int m = 1; m < 64; m <<= 1) ss += __shfl_xor(ss, m, 64);
  const float r = 1.0f / fmaxf(sqrtf(ss), 1e-12f);
  ushort4 o0, o1;
  o0.x = f2bf(v0.x * r); o0.y = f2bf(v0.y * r);
  o0.z = f2bf(v0.z * r); o0.w = f2bf(v0.w * r);
  o1.x = f2bf(v1.x * r); o1.y = f2bf(v1.y * r);
  o1.z = f2bf(v1.z * r); o1.w = f2bf(v1.w * r);
  ushort4* d4 = (ushort4*)(zn + (size_t)row * DIM);
  d4[l]      = o0;
  d4[l + 64] = o1;
}

// ---------------------------------------------------------------- main GEMM
// Compact triangular grid: 2080 blocks, block t -> (bi, bj) with bi <= bj.
// Off-diagonal blocks contribute row-sums to S[rows] AND col-sums to S[cols].
// Positives extracted on bj == bi+32 blocks (block-local diagonal).
// Double-buffered LDS: prefetch K-tile k+1 while computing k, ONE barrier per
// iter; the barrier's vmcnt(0) drain waits on loads issued a full compute
// phase earlier -> staging latency hidden inside the block.
// LDS XOR swizzle (chunk c holds k-chunk (c&3)^((c>>3)&3)): zero bank
// conflicts (verified R2).
__global__ __launch_bounds__(256) void simsum_kernel(const ushort* __restrict__ zn,
                                                     float* __restrict__ S,
                                                     float* __restrict__ P) {
  // triangle decode: u = bj*(bj+1)/2 + bi, bi <= bj < 64
  const int u = blockIdx.x;
  int bj = (int)((sqrtf(8.0f * (float)u + 1.0f) - 1.0f) * 0.5f);
  while ((bj + 1) * (bj + 2) / 2 <= u) ++bj;
  while (bj * (bj + 1) / 2 > u) --bj;
  const int bi = u - bj * (bj + 1) / 2;
  const bool diag = (bi == bj);
  const bool posb = (bj == bi + BATCH / 128);

  __shared__ __align__(16) ushort shA[2 * 4096];
  __shared__ __align__(16) ushort shB[2 * 4096];
  __shared__ float redR[2][128];
  __shared__ float redC[2][128];

  const int t    = threadIdx.x;
  const int w    = t >> 6;
  const int l    = t & 63;
  const int quad = l >> 4;
  const int lo   = l & 15;
  const int wm   = w >> 1;
  const int wn   = w & 1;
  const int tileRow = bi * 128;
  const int tileCol = bj * 128;

  // staging: lane l of wave w stages chunks c0 = w*128+l and c1 = c0+64 into
  // LDS at chunk*16B (wave-uniform base + lane*16). Source k-chunk XOR-swizzled.
  const int c0 = w * 128 + l;
  const int c1 = c0 + 64;
  const int r0 = c0 >> 2, k0 = ((c0 & 3) ^ ((r0 >> 1) & 3)) * 8;
  const int r1 = c1 >> 2, k1 = ((c1 & 3) ^ ((r1 >> 1) & 3)) * 8;
  const ushort* gA0 = zn + (size_t)(tileRow + r0) * DIM + k0;
  const ushort* gA1 = zn + (size_t)(tileRow + r1) * DIM + k1;
  const ushort* gB0 = zn + (size_t)(tileCol + r0) * DIM + k0;
  const ushort* gB1 = zn + (size_t)(tileCol + r1) * DIM + k1;
  ushort* lA0 = shA + w * 1024;
  ushort* lA1 = shA + w * 1024 + 512;
  ushort* lB0 = shB + w * 1024;
  ushort* lB1 = shB + w * 1024 + 512;

  floatx4 acc[4][4];
  #pragma unroll
  for (int i = 0; i < 4; ++i)
    #pragma unroll
    for (int j = 0; j < 4; ++j)
      acc[i][j] = (floatx4){0.f, 0.f, 0.f, 0.f};

  // fragment read offsets (ushorts): chunk = R*4 + (quad ^ ((lo>>1)&3))
  const int sw   = (quad ^ ((lo >> 1) & 3)) * 8;
  const int aOff = (wm * 64 + lo) * 32 + sw;  // + i*512
  const int bOff = (wn * 64 + lo) * 32 + sw;  // + j*512

  // prologue: stage K-tile 0 into buffer 0
  ASYNC16(gA0, lA0); ASYNC16(gA1, lA1);
  ASYNC16(gB0, lB0); ASYNC16(gB1, lB1);
  gA0 += 32; gA1 += 32; gB0 += 32; gB1 += 32;

  #pragma unroll
  for (int it = 0; it < 16; ++it) {
    __syncthreads();  // drains loads for buffer `cur` (issued one iter ago)
    const int co = (it & 1) * 4096;
    const int no = co ^ 4096;
    if (it < 15) {
      ASYNC16(gA0, lA0 + no); ASYNC16(gA1, lA1 + no);
      ASYNC16(gB0, lB0 + no); ASYNC16(gB1, lB1 + no);
      gA0 += 32; gA1 += 32; gB0 += 32; gB1 += 32;
    }
    bf16x8 aF[4], bF[4];
    #pragma unroll
    for (int i = 0; i < 4; ++i) aF[i] = *(const bf16x8*)(shA + co + aOff + i * 512);
    #pragma unroll
    for (int j = 0; j < 4; ++j) bF[j] = *(const bf16x8*)(shB + co + bOff + j * 512);
    #pragma unroll
    for (int i = 0; i < 4; ++i)
      #pragma unroll
      for (int j = 0; j < 4; ++j)
        acc[i][j] = __builtin_amdgcn_mfma_f32_16x16x32_bf16(aF[i], bF[j],
                                                            acc[i][j], 0, 0, 0);
  }

  // ---- epilogue. C/D layout: col = lo, row = quad*4 + r (within 16x16)
  float rs[4][4];
  float cs[4];
  #pragma unroll
  for (int i = 0; i < 4; ++i)
    #pragma unroll
    for (int r = 0; r < 4; ++r) rs[i][r] = 0.f;
  #pragma unroll
  for (int j = 0; j < 4; ++j) cs[j] = 0.f;

  #pragma unroll
  for (int i = 0; i < 4; ++i)
    #pragma unroll
    for (int j = 0; j < 4; ++j)
      #pragma unroll
      for (int r = 0; r < 4; ++r) {
        const float e = __expf(acc[i][j][r] * 10.0f - 10.0f);
        rs[i][r] += e;
        cs[j] += e;
      }

  // block-local diagonal lanes: wm==wn, lo == quad*4 + r  (i.e. quad == lo>>2)
  if (wm == wn && quad == (lo >> 2)) {
    const int r = lo & 3;
    if (diag) {  // self-similarity: remove exp from both row and col sums
      #pragma unroll
      for (int i = 0; i < 4; ++i) {
        const float e = __expf(acc[i][i][r] * 10.0f - 10.0f);
        rs[i][r] -= e;
        cs[i] -= e;
      }
    }
    if (posb) {  // positives: col == row + BATCH
      #pragma unroll
      for (int i = 0; i < 4; ++i) {
        const int row = tileRow + wm * 64 + i * 16 + lo;
        const float v = acc[i][i][r] * 10.0f;
        P[row] = v;
        P[row + BATCH] = v;
      }
    }
  }

  // row sums: reduce across the 16 column-lanes (low 4 lane bits)
  #pragma unroll
  for (int m = 1; m < 16; m <<= 1) {
    #pragma unroll
    for (int i = 0; i < 4; ++i)
      #pragma unroll
      for (int r = 0; r < 4; ++r)
        rs[i][r] += __shfl_xor(rs[i][r], m, 64);
  }
  if (lo == 0) {
    #pragma unroll
    for (int i = 0; i < 4; ++i)
      #pragma unroll
      for (int r = 0; r < 4; ++r)
        redR[wn][wm * 64 + i * 16 + quad * 4 + r] = rs[i][r];
  }
  // col sums: reduce across the 4 quads (lane bits 4,5)
  #pragma unroll
  for (int m = 16; m < 64; m <<= 1) {
    #pragma unroll
    for (int j = 0; j < 4; ++j) cs[j] += __shfl_xor(cs[j], m, 64);
  }
  if (quad == 0) {
    #pragma unroll
    for (int j = 0; j < 4; ++j)
      redC[wm][wn * 64 + j * 16 + lo] = cs[j];
  }
  __syncthreads();
  if (t < 128) {
    atomicAdd(&S[tileRow + t], redR[0][t] + redR[1][t]);
  } else if (!diag) {
    const int c = t - 128;
    atomicAdd(&S[tileCol + c], redC[0][c] + redC[1][c]);
  }
}

// ---------------------------------------------------------------- final loss
__global__ __launch_bounds__(256) void loss_kernel(const float* __restrict__ S,
                                                   const float* __restrict__ P,
                                                   float* __restrict__ out) {
  float acc = 0.f;
  for (int i = threadIdx.x; i < NTOT; i += 256)
    acc += 10.0f + logf(S[i]) - P[i];
  #pragma unroll
  for (int m = 1; m < 64; m <<= 1) acc += __shfl_xor(acc, m, 64);
  __shared__ float sb[4];
  if ((threadIdx.x & 63) == 0) sb[threadIdx.x >> 6] = acc;
  __syncthreads();
  if (threadIdx.x == 0)
    out[0] = (sb[0] + sb[1] + sb[2] + sb[3]) / (float)NTOT;
}

extern "C" void kernel_launch(void* const* d_in, const int* in_sizes, int n_in,
                              void* d_out, int out_size, void* d_ws, size_t ws_size,
                              hipStream_t stream) {
  const float* zi = (const float*)d_in[0];
  const float* zj = (const float*)d_in[1];
  ushort* zn = (ushort*)d_ws;                                  // 8192*512 bf16 = 8 MB
  float*  S  = (float*)((char*)d_ws + (size_t)NTOT * DIM * 2); // 32 KB
  float*  P  = S + NTOT;                                       // 32 KB
  float*  out = (float*)d_out;

  nrm_kernel<<<NTOT / 4, 256, 0, stream>>>(zi, zj, zn, S);
  simsum_kernel<<<2080, 256, 0, stream>>>(zn, S, P);
  loss_kernel<<<1, 256, 0, stream>>>(S, P, out);
}